// Round 13
// baseline (1656.326 us; speedup 1.0000x reference)
//
#include <hip/hip_runtime.h>

namespace {

typedef _Float16 h2 __attribute__((ext_vector_type(2)));
typedef _Float16 f16x8 __attribute__((ext_vector_type(8)));
typedef float    f32x4 __attribute__((ext_vector_type(4)));

constexpr int KSTEPS = 512;
constexpr int NSTATE = 128;
constexpr int NINPUT = 32;
constexpr int HID    = 256;
constexpr int FANIN  = 161;
constexpr int BATCH  = 64;
constexpr int CHUNK  = 64;    // k4 time-chunk
constexpr int NCH    = 8;

// ---- workspace layout (bytes) ----
constexpr size_t WS_M  = 0;                                   // 256x256 f16 (M = W1y*W2)
constexpr size_t WS_C  = WS_M + (size_t)HID * HID * 2;        // 256 f32    (c = W1y*b2)
constexpr size_t WS_US = WS_C + HID * 4;                      // B*K*32 f16
constexpr size_t WS_HB = WS_US + (size_t)BATCH * KSTEPS * NINPUT * 2;   // B*K*256 f16
constexpr size_t WS_T  = WS_HB + (size_t)BATCH * KSTEPS * HID * 2;      // B*8*256 f32

__device__ __forceinline__ float fdot2(h2 a, h2 b, float c) {
#if __has_builtin(__builtin_amdgcn_fdot2)
  return __builtin_amdgcn_fdot2(a, b, c, false);
#else
  return c + (float)a[0] * (float)b[0] + (float)a[1] * (float)b[1];
#endif
}

// tanh(x) = 1 - 2/(exp(2x)+1) via v_exp + v_rcp (no f32 divide sequence).
__device__ __forceinline__ float fast_tanh(float x) {
  float e2 = __builtin_amdgcn_exp2f(x * 2.8853900817779268f);   // exp(2x)
  float r  = __builtin_amdgcn_rcpf(e2 + 1.0f);
  return __builtin_fmaf(-2.0f, r, 1.0f);
}

#define BAR() __asm__ volatile("s_waitcnt lgkmcnt(0)\n\ts_barrier" ::: "memory")

union F4 { float4 f; h2 h[4]; };

// ---------- K1: M = W1y*W2 (f16), c = W1y*b2 (f32) ----------
__global__ __launch_bounds__(256)
void k1_compose(const float* __restrict__ W1, const float* __restrict__ W2,
                const float* __restrict__ b2, _Float16* __restrict__ wsM,
                float* __restrict__ wsC) {
  const int j  = blockIdx.x;
  const int hc = threadIdx.x;
  const float* w1row = W1 + (size_t)j * FANIN + 1;
  float acc = 0.0f;
  for (int o = 0; o < NSTATE; ++o)
    acc = __builtin_fmaf(w1row[o], W2[(size_t)o * HID + hc], acc);
  wsM[(size_t)j * HID + hc] = (_Float16)acc;
  if (hc == 0) {
    float ca = 0.0f;
    for (int o = 0; o < NSTATE; ++o) ca = __builtin_fmaf(w1row[o], b2[o], ca);
    wsC[j] = ca;
  }
}

// ---------- K1b: transcode us (f32 -> f16) ----------
__global__ __launch_bounds__(256)
void k1b_transcode(const float* __restrict__ us, _Float16* __restrict__ us16) {
  const size_t idx = ((size_t)blockIdx.x * 256 + threadIdx.x) * 4;
  const float4 v = *(const float4*)(us + idx);
  us16[idx + 0] = (_Float16)v.x;
  us16[idx + 1] = (_Float16)v.y;
  us16[idx + 2] = (_Float16)v.z;
  us16[idx + 3] = (_Float16)v.w;
}

// ---------- K2: COLUMN-PACKED dual-trajectory MFMA (R11) + chain shortening ----------
// R12 (setprio) was null -> wall ~1130cyc/stage is the sync+dependency
// envelope, invariant to scheduling hints. This round removes the last two
// critical-chain components that COULD still be exposed:
//  * u-dot (Ub) + D hoisted from stage e==0 to loop top: its 16-fdot2 chain
//    no longer sits between stage-0's barrier and tail;
//  * each 8-deep MFMA accumulation chain split into two independent depth-4
//    chains + one f32x4 add (halves MFMA latency term if latency-bound).
// setprio reverted. Numerics identical to R11 (same values, reordered).
__global__ __launch_bounds__(512)
__attribute__((amdgpu_waves_per_eu(2, 2)))
void k2_main(const float* __restrict__ ts,
             const float* __restrict__ y0,
             const float* __restrict__ W1,
             const float* __restrict__ b1,
             char* __restrict__ ws)
{
  const int lt  = threadIdx.x;         // 0..511
  const int w   = lt >> 6;             // wave 0..7: row-tiles 2w, 2w+1
  const int ln  = lt & 63;             // lane
  const int c   = ln & 15;             // D column
  const int q   = ln >> 4;             // k-frag selector
  const int klo = q * 8;
  const int traj = c >> 3;             // 0 = traj A, 1 = traj B
  const int j   = 32 * w + 16 * (c & 1) + 4 * q + ((c >> 1) & 3);
  const int blk = blockIdx.x;
  const int b   = 2 * blk + traj;      // this thread's trajectory

  const _Float16* wsM  = (const _Float16*)(ws + WS_M);
  const float*    wsC  = (const float*)(ws + WS_C);
  const _Float16* usbase = (const _Float16*)(ws + WS_US) + (size_t)(2 * blk) * KSTEPS * NINPUT;
  _Float16*       wsHB = (_Float16*)(ws + WS_HB) + (size_t)b * KSTEPS * HID;
  float*          wsT  = (float*)(ws + WS_T) + (size_t)b * NCH * HID;

  // h double buffer per trajectory; 272-pad shifts traj B 16 banks (write
  // halves land on disjoint bank ranges).
  __shared__ __align__(16) _Float16 hbuf[2][2][272];
  __shared__ __align__(16) float y0s[2][NSTATE];
  __shared__ __align__(16) float tss[KSTEPS];                 // 2 KB
  __shared__ __align__(16) _Float16 usl[2][KSTEPS * NINPUT];  // 64 KB

  // ---- one-time staging: both trajectories' us slabs + ts ----
  {
    const F4* s0 = (const F4*)(usbase);
    const F4* s1 = (const F4*)(usbase + (size_t)KSTEPS * NINPUT);
    F4* d0 = (F4*)usl[0];
    F4* d1 = (F4*)usl[1];
    #pragma unroll
    for (int it = 0; it < 4; ++it) {
      d0[lt + 512 * it] = s0[lt + 512 * it];
      d1[lt + 512 * it] = s1[lt + 512 * it];
    }
    tss[lt] = ts[lt];
  }

  // ---- A fragments: wave w covers row-tiles 2w, 2w+1 (M shared by trajs) ----
  f16x8 af[2][8];
  #pragma unroll
  for (int t = 0; t < 2; ++t) {
    const int row = 32 * w + 16 * t + (ln & 15);
    #pragma unroll
    for (int kk = 0; kk < 8; ++kk)
      af[t][kk] = *(const f16x8*)(wsM + (size_t)row * HID + kk * 32 + klo);
  }

  // ---- per-owner-row constants (weights shared; keyed to j) ----
  const float* w1row = W1 + (size_t)j * FANIN;
  const float  w1t   = w1row[0];
  h2 w1u[16];
  #pragma unroll
  for (int i = 0; i < 16; ++i)
    w1u[i] = h2{(_Float16)w1row[129 + 2 * i], (_Float16)w1row[130 + 2 * i]};
  const float cR = wsC[j];

  // ---- P = W1y*y0 + b1 (fp32), y0 of OWN trajectory ----
  if (lt < 2 * NSTATE)
    y0s[lt >> 7][lt & 127] = y0[(size_t)(2 * blk + (lt >> 7)) * NSTATE + (lt & 127)];
  __syncthreads();   // staging + y0s visible
  float P = b1[j];
  {
    const float* wy = w1row + 1;
    #pragma unroll 8
    for (int o = 0; o < NSTATE; ++o) P = __builtin_fmaf(wy[o], y0s[traj][o], P);
  }

  constexpr double CcD[5] = {0.161, 0.327, 0.9, 0.9800255409045097, 1.0};
  constexpr float Af[5][5] = {
    {0.161f, 0.f, 0.f, 0.f, 0.f},
    {-0.008480655492356989f, 0.335480655492357f, 0.f, 0.f, 0.f},
    {2.8971530571054935f, -6.359448489975075f, 4.3622954328695815f, 0.f, 0.f},
    {5.325864828439257f, -11.748883564062828f, 7.4955393428898365f, -0.09249506636175525f, 0.f},
    {5.86145544294642f, -12.92096931784711f, 8.159367898576159f, -0.071584973281401f,
     -0.028269050394068383f}};
  constexpr float Bf[6] = {0.09646076681806523f, 0.01f, 0.4798896504144996f,
                           1.379008574103742f, -3.290069515436081f, 2.324710524099774f};

  // ---- init: Ua = W1u*u_0 (from own slab) ----
  float Ua, Ub = 0.0f, Uaprev = 0.0f, D = 0.0f;
  {
    const F4* up = (const F4*)(usl[traj]);
    F4 u0 = up[0], u1 = up[1], u2 = up[2], u3 = up[3];
    float s = 0.0f;
    #pragma unroll
    for (int i = 0; i < 4; ++i) {
      s = fdot2(w1u[i],      u0.h[i], s);
      s = fdot2(w1u[4 + i],  u1.h[i], s);
      s = fdot2(w1u[8 + i],  u2.h[i], s);
      s = fdot2(w1u[12 + i], u3.h[i], s);
    }
    Ua = s;
  }

  float tcur = ts[0], tn1 = ts[1];
  float dtp = 1.0f;
  float h0v = fast_tanh(P + Ua + w1t * tcur);
  hbuf[traj][0][j] = (_Float16)h0v;
  float hB = Bf[0] * h0v;
  float Sacc = 0.0f;
  float aR[6];

  for (int i = 0; i < KSTEPS - 1; ++i) {
    const float dt = tn1 - tcur;
    const int   i2 = (i + 2 < KSTEPS) ? (i + 2) : (KSTEPS - 1);
    const float tn2 = tss[i2];

    // ---- u-dot HOISTED: Ub, D computed at loop top, off the stage-0
    //      barrier->tail critical chain (identical values) ----
    {
      const F4* up = (const F4*)(&usl[traj][(i + 1) * NINPUT]);
      F4 ur0 = up[0], ur1 = up[1], ur2 = up[2], ur3 = up[3];
      float s = 0.0f;
      #pragma unroll
      for (int qq = 0; qq < 4; ++qq) {
        s = fdot2(w1u[qq],      ur0.h[qq], s);
        s = fdot2(w1u[4 + qq],  ur1.h[qq], s);
        s = fdot2(w1u[8 + qq],  ur2.h[qq], s);
        s = fdot2(w1u[12 + qq], ur3.h[qq], s);
      }
      Ub = s;
      D = (i == 0) ? (Ub - Ua)
                   : (Ua - Uaprev) * (dt * __builtin_amdgcn_rcpf(dtp));
    }

    if (i > 0 && (i & (CHUNK - 1)) == 0)
      wsT[(size_t)(i >> 6) * HID + j] = Sacc;

    #pragma unroll
    for (int e = 0; e < 6; ++e) {
      BAR();   // h_e ready in hbuf[*][e&1]

      // ---- B fragments: column c carries h of trajectory c>>3 ----
      const _Float16* hb = hbuf[traj][e & 1];
      f16x8 bf[8];
      #pragma unroll
      for (int kk = 0; kk < 8; ++kk)
        bf[kk] = *(const f16x8*)(hb + kk * 32 + klo);

      if (e == 5) {
        wsHB[(size_t)i * HID + j] = (_Float16)hB;   // hB complete: fire & forget
      }

      // ---- one MFMA job = matvec for BOTH trajectories.
      //      2 independent depth-4 chains per row-tile + f32x4 add:
      //      halves the MFMA-latency term of the stage chain. ----
      f32x4 ac0a = {0.f, 0.f, 0.f, 0.f};
      f32x4 ac1a = {0.f, 0.f, 0.f, 0.f};
      f32x4 ac0b = {0.f, 0.f, 0.f, 0.f};
      f32x4 ac1b = {0.f, 0.f, 0.f, 0.f};
      #pragma unroll
      for (int kk = 0; kk < 4; ++kk) {
        ac0a = __builtin_amdgcn_mfma_f32_16x16x32_f16(af[0][kk],     bf[kk],     ac0a, 0, 0, 0);
        ac1a = __builtin_amdgcn_mfma_f32_16x16x32_f16(af[1][kk],     bf[kk],     ac1a, 0, 0, 0);
        ac0b = __builtin_amdgcn_mfma_f32_16x16x32_f16(af[0][kk + 4], bf[kk + 4], ac0b, 0, 0, 0);
        ac1b = __builtin_amdgcn_mfma_f32_16x16x32_f16(af[1][kk + 4], bf[kk + 4], ac1b, 0, 0, 0);
      }
      const f32x4 ac0 = ac0a + ac0b;
      const f32x4 ac1 = ac1a + ac1b;

      // ---- select owned value: tile = c&1, reg = (c>>1)&3 (R8-verified) ----
      float ae;
      {
        const bool tsel = (c & 1) != 0;
        float v0 = tsel ? ac1[0] : ac0[0];
        float v1 = tsel ? ac1[1] : ac0[1];
        float v2 = tsel ? ac1[2] : ac0[2];
        float v3 = tsel ? ac1[3] : ac0[3];
        const bool r0 = (c & 2) != 0;
        const bool r1 = (c & 4) != 0;
        ae = r1 ? (r0 ? v3 : v2) : (r0 ? v1 : v0);
      }
      ae += cR;
      aR[e] = ae;

      if (e < 5) {
        float acm = 0.0f;
        #pragma unroll
        for (int mm = 0; mm <= e; ++mm) acm = __builtin_fmaf(Af[e][mm], aR[mm], acm);
        const double th = CcD[e];
        const float cu0 = (float)(th * th * th - 2.0 * th * th + 1.0);
        const float cu1 = (float)(2.0 * th * th - th * th * th);
        const float cd0 = (float)(th * th * th - 2.0 * th * th + th);
        const float ut  = cu0 * Ua + cu1 * Ub + cd0 * D;
        const float te  = __builtin_fmaf((float)th, dt, tcur);
        float pre = __builtin_fmaf(dt, acm, P) + ut;
        pre = __builtin_fmaf(w1t, te, pre);
        const float hv = fast_tanh(pre);
        hbuf[traj][(e + 1) & 1][j] = (_Float16)hv;
        hB = __builtin_fmaf(Bf[e + 1], hv, hB);
      } else {
        float acm = 0.0f;
        #pragma unroll
        for (int mm = 0; mm < 6; ++mm) acm = __builtin_fmaf(Bf[mm], aR[mm], acm);
        P = __builtin_fmaf(dt, acm, P);
        Sacc = __builtin_fmaf(dt, hB, Sacc);     // S accumulates BEFORE hB reset
        float pre = P + Ub;                      // u(theta=0) of next step = u_{i+1}
        pre = __builtin_fmaf(w1t, tn1, pre);
        const float hv = fast_tanh(pre);
        hbuf[traj][0][j] = (_Float16)hv;
        hB = Bf[0] * hv;
      }
    }

    Uaprev = Ua; Ua = Ub;
    dtp = dt; tcur = tn1; tn1 = tn2;
  }
}

// ---------- K4: out[b][i+1] = y0 + W2*S_i, time-chunk parallel (512 blocks) ----------
__global__ __launch_bounds__(256, 1)
void k4_out(const float* __restrict__ ts,
            const float* __restrict__ y0,
            const float* __restrict__ W2,
            const char* __restrict__ ws,
            float* __restrict__ out)
{
  const int blk = blockIdx.x;
  const int b = blk >> 3;
  const int c = blk & 7;
  const int lt = threadIdx.x;
  const int o    = lt >> 1;
  const int half = lt & 1;

  const _Float16* wsHB = (const _Float16*)(ws + WS_HB) + (size_t)b * KSTEPS * HID;
  const float*    wsT  = (const float*)(ws + WS_T) + (size_t)b * NCH * HID;
  float* outb = out + (size_t)b * KSTEPS * NSTATE;

  __shared__ __align__(16) _Float16 Sb[HID];

  h2 w2r[64];
  {
    const float* row = W2 + (size_t)o * HID + 128 * half;
    #pragma unroll
    for (int i = 0; i < 64; ++i)
      w2r[i] = h2{(_Float16)row[2 * i], (_Float16)row[2 * i + 1]};
  }
  const float y0o = y0[(size_t)b * NSTATE + o];
  if (c == 0 && lt < NSTATE) outb[lt] = y0[(size_t)b * NSTATE + lt];

  float S = (c > 0) ? wsT[(size_t)c * HID + lt] : 0.0f;
  const int i0 = c * CHUNK;
  const int n  = (KSTEPS - 1 - i0 < CHUNK) ? (KSTEPS - 1 - i0) : CHUNK;

  float tc = ts[i0], tn = ts[i0 + 1];
  float hcur = (float)wsHB[(size_t)i0 * HID + lt];
  for (int l = 0; l < n; ++l) {
    const int i = i0 + l;
    const int inx = (i + 1 < KSTEPS - 1) ? (i + 1) : (KSTEPS - 2);
    const float hnext = (float)wsHB[(size_t)inx * HID + lt];
    const float tnn = ts[(i + 2 < KSTEPS) ? (i + 2) : (KSTEPS - 1)];

    const float dt = tn - tc;
    S = __builtin_fmaf(dt, hcur, S);
    Sb[lt] = (_Float16)S;
    __syncthreads();

    const F4* sp = (const F4*)(&Sb[128 * half]);
    float v0 = 0.0f, v1 = 0.0f;
    #pragma unroll
    for (int q = 0; q < 16; ++q) {
      F4 sc = sp[q];
      v0 = fdot2(w2r[4 * q + 0], sc.h[0], v0);
      v1 = fdot2(w2r[4 * q + 1], sc.h[1], v1);
      v0 = fdot2(w2r[4 * q + 2], sc.h[2], v0);
      v1 = fdot2(w2r[4 * q + 3], sc.h[3], v1);
    }
    float v = v0 + v1;
    v += __shfl_xor(v, 1);
    if (half == 0) outb[(size_t)(i + 1) * NSTATE + o] = y0o + v;
    __syncthreads();

    hcur = hnext; tc = tn; tn = tnn;
  }
}

} // namespace

extern "C" void kernel_launch(void* const* d_in, const int* in_sizes, int n_in,
                              void* d_out, int out_size, void* d_ws, size_t ws_size,
                              hipStream_t stream) {
  const float* ts = (const float*)d_in[0];
  const float* y0 = (const float*)d_in[1];
  const float* us = (const float*)d_in[2];
  const float* W1 = (const float*)d_in[3];
  const float* b1 = (const float*)d_in[4];
  const float* W2 = (const float*)d_in[5];
  const float* b2 = (const float*)d_in[6];
  float* out = (float*)d_out;
  char* ws = (char*)d_ws;

  _Float16* wsM  = (_Float16*)(ws + WS_M);
  float*    wsC  = (float*)(ws + WS_C);
  _Float16* us16 = (_Float16*)(ws + WS_US);

  hipLaunchKernelGGL(k1_compose, dim3(HID), dim3(HID), 0, stream, W1, W2, b2, wsM, wsC);
  hipLaunchKernelGGL(k1b_transcode, dim3(BATCH * KSTEPS * NINPUT / 1024), dim3(256),
                     0, stream, us, us16);
  hipLaunchKernelGGL(k2_main, dim3(BATCH / 2), dim3(512), 0, stream, ts, y0, W1, b1, ws);
  hipLaunchKernelGGL(k4_out, dim3(BATCH * NCH), dim3(256), 0, stream, ts, y0, W2,
                     (const char*)ws, out);
}

// Round 14
// 1535.380 us; speedup vs baseline: 1.0788x; 1.0788x over previous
//
#include <hip/hip_runtime.h>

namespace {

typedef _Float16 h2 __attribute__((ext_vector_type(2)));
typedef _Float16 f16x8 __attribute__((ext_vector_type(8)));
typedef float    f32x4 __attribute__((ext_vector_type(4)));

constexpr int KSTEPS = 512;
constexpr int NSTATE = 128;
constexpr int NINPUT = 32;
constexpr int HID    = 256;
constexpr int FANIN  = 161;
constexpr int BATCH  = 64;
constexpr int CHUNK  = 64;    // k4 time-chunk
constexpr int NCH    = 8;

// ---- workspace layout (bytes) ----
constexpr size_t WS_M  = 0;                                   // 256x256 f16 (M = W1y*W2)
constexpr size_t WS_C  = WS_M + (size_t)HID * HID * 2;        // 256 f32    (c = W1y*b2)
constexpr size_t WS_US = WS_C + HID * 4;                      // B*K*32 f16
constexpr size_t WS_HB = WS_US + (size_t)BATCH * KSTEPS * NINPUT * 2;   // B*K*256 f16
constexpr size_t WS_T  = WS_HB + (size_t)BATCH * KSTEPS * HID * 2;      // B*8*256 f32

__device__ __forceinline__ float fdot2(h2 a, h2 b, float c) {
#if __has_builtin(__builtin_amdgcn_fdot2)
  return __builtin_amdgcn_fdot2(a, b, c, false);
#else
  return c + (float)a[0] * (float)b[0] + (float)a[1] * (float)b[1];
#endif
}

// tanh(x) = 1 - 2/(exp(2x)+1) via v_exp + v_rcp (no f32 divide sequence).
__device__ __forceinline__ float fast_tanh(float x) {
  float e2 = __builtin_amdgcn_exp2f(x * 2.8853900817779268f);   // exp(2x)
  float r  = __builtin_amdgcn_rcpf(e2 + 1.0f);
  return __builtin_fmaf(-2.0f, r, 1.0f);
}

#define BAR() __asm__ volatile("s_waitcnt lgkmcnt(0)\n\ts_barrier" ::: "memory")

union F4 { float4 f; h2 h[4]; };

// ---------- K1: M = W1y*W2 (f16), c = W1y*b2 (f32) ----------
__global__ __launch_bounds__(256)
void k1_compose(const float* __restrict__ W1, const float* __restrict__ W2,
                const float* __restrict__ b2, _Float16* __restrict__ wsM,
                float* __restrict__ wsC) {
  const int j  = blockIdx.x;
  const int hc = threadIdx.x;
  const float* w1row = W1 + (size_t)j * FANIN + 1;
  float acc = 0.0f;
  for (int o = 0; o < NSTATE; ++o)
    acc = __builtin_fmaf(w1row[o], W2[(size_t)o * HID + hc], acc);
  wsM[(size_t)j * HID + hc] = (_Float16)acc;
  if (hc == 0) {
    float ca = 0.0f;
    for (int o = 0; o < NSTATE; ++o) ca = __builtin_fmaf(w1row[o], b2[o], ca);
    wsC[j] = ca;
  }
}

// ---------- K1b: transcode us (f32 -> f16) ----------
__global__ __launch_bounds__(256)
void k1b_transcode(const float* __restrict__ us, _Float16* __restrict__ us16) {
  const size_t idx = ((size_t)blockIdx.x * 256 + threadIdx.x) * 4;
  const float4 v = *(const float4*)(us + idx);
  us16[idx + 0] = (_Float16)v.x;
  us16[idx + 1] = (_Float16)v.y;
  us16[idx + 2] = (_Float16)v.z;
  us16[idx + 3] = (_Float16)v.w;
}

// ---------- K2: COLUMN-PACKED dual-trajectory MFMA (R11, best verified) ----------
// Final structure. B columns 0-7 carry traj A's h, 8-15 carry traj B's h:
// one 128-MFMA job per block computes BOTH trajectories' matvecs (32
// MFMA/SIMD issue) while 2 waves/SIMD hide chain/LDS latency. Lane
// (c=ln&15, q=ln>>4) owns (traj=c>>3, row j=32w+16(c&1)+4q+((c>>1)&3)) --
// all 512 threads own distinct (traj,row), full tail per thread, no write
// masking. Measured wall ~1120cyc/stage; structural floor = 6-stage serial
// RK dependency x (620cyc MFMA issue + ~500cyc sync/tail envelope).
// Scheduling attacks (anti-phase, dual-pipe, setprio, chain-split, u-dot
// hoist) were all null or negative (R6/R7/R12/R13).
__global__ __launch_bounds__(512)
__attribute__((amdgpu_waves_per_eu(2, 2)))
void k2_main(const float* __restrict__ ts,
             const float* __restrict__ y0,
             const float* __restrict__ W1,
             const float* __restrict__ b1,
             char* __restrict__ ws)
{
  const int lt  = threadIdx.x;         // 0..511
  const int w   = lt >> 6;             // wave 0..7: row-tiles 2w, 2w+1
  const int ln  = lt & 63;             // lane
  const int c   = ln & 15;             // D column
  const int q   = ln >> 4;             // k-frag selector
  const int klo = q * 8;
  const int traj = c >> 3;             // 0 = traj A, 1 = traj B
  const int j   = 32 * w + 16 * (c & 1) + 4 * q + ((c >> 1) & 3);
  const int blk = blockIdx.x;
  const int b   = 2 * blk + traj;      // this thread's trajectory

  const _Float16* wsM  = (const _Float16*)(ws + WS_M);
  const float*    wsC  = (const float*)(ws + WS_C);
  const _Float16* usbase = (const _Float16*)(ws + WS_US) + (size_t)(2 * blk) * KSTEPS * NINPUT;
  _Float16*       wsHB = (_Float16*)(ws + WS_HB) + (size_t)b * KSTEPS * HID;
  float*          wsT  = (float*)(ws + WS_T) + (size_t)b * NCH * HID;

  // h double buffer per trajectory; 272-pad shifts traj B 16 banks (write
  // halves land on disjoint bank ranges).
  __shared__ __align__(16) _Float16 hbuf[2][2][272];
  __shared__ __align__(16) float y0s[2][NSTATE];
  __shared__ __align__(16) float tss[KSTEPS];                 // 2 KB
  __shared__ __align__(16) _Float16 usl[2][KSTEPS * NINPUT];  // 64 KB

  // ---- one-time staging: both trajectories' us slabs + ts ----
  {
    const F4* s0 = (const F4*)(usbase);
    const F4* s1 = (const F4*)(usbase + (size_t)KSTEPS * NINPUT);
    F4* d0 = (F4*)usl[0];
    F4* d1 = (F4*)usl[1];
    #pragma unroll
    for (int it = 0; it < 4; ++it) {
      d0[lt + 512 * it] = s0[lt + 512 * it];
      d1[lt + 512 * it] = s1[lt + 512 * it];
    }
    tss[lt] = ts[lt];
  }

  // ---- A fragments: wave w covers row-tiles 2w, 2w+1 (M shared by trajs) ----
  f16x8 af[2][8];
  #pragma unroll
  for (int t = 0; t < 2; ++t) {
    const int row = 32 * w + 16 * t + (ln & 15);
    #pragma unroll
    for (int kk = 0; kk < 8; ++kk)
      af[t][kk] = *(const f16x8*)(wsM + (size_t)row * HID + kk * 32 + klo);
  }

  // ---- per-owner-row constants (weights shared; keyed to j) ----
  const float* w1row = W1 + (size_t)j * FANIN;
  const float  w1t   = w1row[0];
  h2 w1u[16];
  #pragma unroll
  for (int i = 0; i < 16; ++i)
    w1u[i] = h2{(_Float16)w1row[129 + 2 * i], (_Float16)w1row[130 + 2 * i]};
  const float cR = wsC[j];

  // ---- P = W1y*y0 + b1 (fp32), y0 of OWN trajectory ----
  if (lt < 2 * NSTATE)
    y0s[lt >> 7][lt & 127] = y0[(size_t)(2 * blk + (lt >> 7)) * NSTATE + (lt & 127)];
  __syncthreads();   // staging + y0s visible
  float P = b1[j];
  {
    const float* wy = w1row + 1;
    #pragma unroll 8
    for (int o = 0; o < NSTATE; ++o) P = __builtin_fmaf(wy[o], y0s[traj][o], P);
  }

  constexpr double CcD[5] = {0.161, 0.327, 0.9, 0.9800255409045097, 1.0};
  constexpr float Af[5][5] = {
    {0.161f, 0.f, 0.f, 0.f, 0.f},
    {-0.008480655492356989f, 0.335480655492357f, 0.f, 0.f, 0.f},
    {2.8971530571054935f, -6.359448489975075f, 4.3622954328695815f, 0.f, 0.f},
    {5.325864828439257f, -11.748883564062828f, 7.4955393428898365f, -0.09249506636175525f, 0.f},
    {5.86145544294642f, -12.92096931784711f, 8.159367898576159f, -0.071584973281401f,
     -0.028269050394068383f}};
  constexpr float Bf[6] = {0.09646076681806523f, 0.01f, 0.4798896504144996f,
                           1.379008574103742f, -3.290069515436081f, 2.324710524099774f};

  // ---- init: Ua = W1u*u_0 (from own slab) ----
  float Ua, Ub = 0.0f, Uaprev = 0.0f, D = 0.0f;
  {
    const F4* up = (const F4*)(usl[traj]);
    F4 u0 = up[0], u1 = up[1], u2 = up[2], u3 = up[3];
    float s = 0.0f;
    #pragma unroll
    for (int i = 0; i < 4; ++i) {
      s = fdot2(w1u[i],      u0.h[i], s);
      s = fdot2(w1u[4 + i],  u1.h[i], s);
      s = fdot2(w1u[8 + i],  u2.h[i], s);
      s = fdot2(w1u[12 + i], u3.h[i], s);
    }
    Ua = s;
  }

  float tcur = ts[0], tn1 = ts[1];
  float dtp = 1.0f;
  float h0v = fast_tanh(P + Ua + w1t * tcur);
  hbuf[traj][0][j] = (_Float16)h0v;
  float hB = Bf[0] * h0v;
  float Sacc = 0.0f;
  float aR[6];

  for (int i = 0; i < KSTEPS - 1; ++i) {
    const float dt = tn1 - tcur;
    const int   i2 = (i + 2 < KSTEPS) ? (i + 2) : (KSTEPS - 1);
    const float tn2 = tss[i2];
    F4 ur0, ur1, ur2, ur3;
    {
      const F4* up = (const F4*)(&usl[traj][(i + 1) * NINPUT]);
      ur0 = up[0]; ur1 = up[1]; ur2 = up[2]; ur3 = up[3];
    }

    if (i > 0 && (i & (CHUNK - 1)) == 0)
      wsT[(size_t)(i >> 6) * HID + j] = Sacc;

    #pragma unroll
    for (int e = 0; e < 6; ++e) {
      BAR();   // h_e ready in hbuf[*][e&1]

      // ---- B fragments: column c carries h of trajectory c>>3 ----
      const _Float16* hb = hbuf[traj][e & 1];
      f16x8 bf[8];
      #pragma unroll
      for (int kk = 0; kk < 8; ++kk)
        bf[kk] = *(const f16x8*)(hb + kk * 32 + klo);

      if (e == 5) {
        wsHB[(size_t)i * HID + j] = (_Float16)hB;   // hB complete: fire & forget
      }
      if (e == 0) {
        float s = 0.0f;
        #pragma unroll
        for (int qq = 0; qq < 4; ++qq) {
          s = fdot2(w1u[qq],      ur0.h[qq], s);
          s = fdot2(w1u[4 + qq],  ur1.h[qq], s);
          s = fdot2(w1u[8 + qq],  ur2.h[qq], s);
          s = fdot2(w1u[12 + qq], ur3.h[qq], s);
        }
        Ub = s;
        D = (i == 0) ? (Ub - Ua)
                     : (Ua - Uaprev) * (dt * __builtin_amdgcn_rcpf(dtp));
      }

      // ---- one MFMA job = matvec for BOTH trajectories ----
      f32x4 ac0 = {0.f, 0.f, 0.f, 0.f};
      f32x4 ac1 = {0.f, 0.f, 0.f, 0.f};
      #pragma unroll
      for (int kk = 0; kk < 8; ++kk) {
        ac0 = __builtin_amdgcn_mfma_f32_16x16x32_f16(af[0][kk], bf[kk], ac0, 0, 0, 0);
        ac1 = __builtin_amdgcn_mfma_f32_16x16x32_f16(af[1][kk], bf[kk], ac1, 0, 0, 0);
      }
      // ---- select owned value: tile = c&1, reg = (c>>1)&3 (R8-verified) ----
      float ae;
      {
        const bool tsel = (c & 1) != 0;
        float v0 = tsel ? ac1[0] : ac0[0];
        float v1 = tsel ? ac1[1] : ac0[1];
        float v2 = tsel ? ac1[2] : ac0[2];
        float v3 = tsel ? ac1[3] : ac0[3];
        const bool r0 = (c & 2) != 0;
        const bool r1 = (c & 4) != 0;
        ae = r1 ? (r0 ? v3 : v2) : (r0 ? v1 : v0);
      }
      ae += cR;
      aR[e] = ae;

      if (e < 5) {
        float acm = 0.0f;
        #pragma unroll
        for (int mm = 0; mm <= e; ++mm) acm = __builtin_fmaf(Af[e][mm], aR[mm], acm);
        const double th = CcD[e];
        const float cu0 = (float)(th * th * th - 2.0 * th * th + 1.0);
        const float cu1 = (float)(2.0 * th * th - th * th * th);
        const float cd0 = (float)(th * th * th - 2.0 * th * th + th);
        const float ut  = cu0 * Ua + cu1 * Ub + cd0 * D;
        const float te  = __builtin_fmaf((float)th, dt, tcur);
        float pre = __builtin_fmaf(dt, acm, P) + ut;
        pre = __builtin_fmaf(w1t, te, pre);
        const float hv = fast_tanh(pre);
        hbuf[traj][(e + 1) & 1][j] = (_Float16)hv;
        hB = __builtin_fmaf(Bf[e + 1], hv, hB);
      } else {
        float acm = 0.0f;
        #pragma unroll
        for (int mm = 0; mm < 6; ++mm) acm = __builtin_fmaf(Bf[mm], aR[mm], acm);
        P = __builtin_fmaf(dt, acm, P);
        Sacc = __builtin_fmaf(dt, hB, Sacc);     // S accumulates BEFORE hB reset
        float pre = P + Ub;                      // u(theta=0) of next step = u_{i+1}
        pre = __builtin_fmaf(w1t, tn1, pre);
        const float hv = fast_tanh(pre);
        hbuf[traj][0][j] = (_Float16)hv;
        hB = Bf[0] * hv;
      }
    }

    Uaprev = Ua; Ua = Ub;
    dtp = dt; tcur = tn1; tn1 = tn2;
  }
}

// ---------- K4: out[b][i+1] = y0 + W2*S_i, time-chunk parallel (512 blocks) ----------
__global__ __launch_bounds__(256, 1)
void k4_out(const float* __restrict__ ts,
            const float* __restrict__ y0,
            const float* __restrict__ W2,
            const char* __restrict__ ws,
            float* __restrict__ out)
{
  const int blk = blockIdx.x;
  const int b = blk >> 3;
  const int c = blk & 7;
  const int lt = threadIdx.x;
  const int o    = lt >> 1;
  const int half = lt & 1;

  const _Float16* wsHB = (const _Float16*)(ws + WS_HB) + (size_t)b * KSTEPS * HID;
  const float*    wsT  = (const float*)(ws + WS_T) + (size_t)b * NCH * HID;
  float* outb = out + (size_t)b * KSTEPS * NSTATE;

  __shared__ __align__(16) _Float16 Sb[HID];

  h2 w2r[64];
  {
    const float* row = W2 + (size_t)o * HID + 128 * half;
    #pragma unroll
    for (int i = 0; i < 64; ++i)
      w2r[i] = h2{(_Float16)row[2 * i], (_Float16)row[2 * i + 1]};
  }
  const float y0o = y0[(size_t)b * NSTATE + o];
  if (c == 0 && lt < NSTATE) outb[lt] = y0[(size_t)b * NSTATE + lt];

  float S = (c > 0) ? wsT[(size_t)c * HID + lt] : 0.0f;
  const int i0 = c * CHUNK;
  const int n  = (KSTEPS - 1 - i0 < CHUNK) ? (KSTEPS - 1 - i0) : CHUNK;

  float tc = ts[i0], tn = ts[i0 + 1];
  float hcur = (float)wsHB[(size_t)i0 * HID + lt];
  for (int l = 0; l < n; ++l) {
    const int i = i0 + l;
    const int inx = (i + 1 < KSTEPS - 1) ? (i + 1) : (KSTEPS - 2);
    const float hnext = (float)wsHB[(size_t)inx * HID + lt];
    const float tnn = ts[(i + 2 < KSTEPS) ? (i + 2) : (KSTEPS - 1)];

    const float dt = tn - tc;
    S = __builtin_fmaf(dt, hcur, S);
    Sb[lt] = (_Float16)S;
    __syncthreads();

    const F4* sp = (const F4*)(&Sb[128 * half]);
    float v0 = 0.0f, v1 = 0.0f;
    #pragma unroll
    for (int q = 0; q < 16; ++q) {
      F4 sc = sp[q];
      v0 = fdot2(w2r[4 * q + 0], sc.h[0], v0);
      v1 = fdot2(w2r[4 * q + 1], sc.h[1], v1);
      v0 = fdot2(w2r[4 * q + 2], sc.h[2], v0);
      v1 = fdot2(w2r[4 * q + 3], sc.h[3], v1);
    }
    float v = v0 + v1;
    v += __shfl_xor(v, 1);
    if (half == 0) outb[(size_t)(i + 1) * NSTATE + o] = y0o + v;
    __syncthreads();

    hcur = hnext; tc = tn; tn = tnn;
  }
}

} // namespace

extern "C" void kernel_launch(void* const* d_in, const int* in_sizes, int n_in,
                              void* d_out, int out_size, void* d_ws, size_t ws_size,
                              hipStream_t stream) {
  const float* ts = (const float*)d_in[0];
  const float* y0 = (const float*)d_in[1];
  const float* us = (const float*)d_in[2];
  const float* W1 = (const float*)d_in[3];
  const float* b1 = (const float*)d_in[4];
  const float* W2 = (const float*)d_in[5];
  const float* b2 = (const float*)d_in[6];
  float* out = (float*)d_out;
  char* ws = (char*)d_ws;

  _Float16* wsM  = (_Float16*)(ws + WS_M);
  float*    wsC  = (float*)(ws + WS_C);
  _Float16* us16 = (_Float16*)(ws + WS_US);

  hipLaunchKernelGGL(k1_compose, dim3(HID), dim3(HID), 0, stream, W1, W2, b2, wsM, wsC);
  hipLaunchKernelGGL(k1b_transcode, dim3(BATCH * KSTEPS * NINPUT / 1024), dim3(256),
                     0, stream, us, us16);
  hipLaunchKernelGGL(k2_main, dim3(BATCH / 2), dim3(512), 0, stream, ts, y0, W1, b1, ws);
  hipLaunchKernelGGL(k4_out, dim3(BATCH * NCH), dim3(256), 0, stream, ts, y0, W2,
                     (const char*)ws, out);
}